// Round 17
// baseline (350.911 us; speedup 1.0000x reference)
//
#include <hip/hip_runtime.h>
#include <hip/hip_bf16.h>
#include <math.h>

namespace {

constexpr int kB = 32;
constexpr int kS = 2048;
constexpr int kI = 32;
constexpr int kW = 20;
constexpr int kH = 128;
constexpr int kNwin = kS - kW + 1;   // 2029
constexpr int kT = kS - 2 * kW;      // 2008
constexpr float kEps = 1e-5f;
constexpr int FCAP = 16384;
constexpr float kMargin = 1e-2f;     // 1-pass bf16 p-error bound ~0.004 << 0.01

typedef __attribute__((ext_vector_type(8))) short short8;          // 8 bf16
typedef __attribute__((ext_vector_type(8))) unsigned short ush8;   // 16B unit
typedef __attribute__((ext_vector_type(4))) float f32x4;

// async global->LDS DMA, 16B per lane; dest = uniform base + lane*16 (linear)
#define GLD16(SRC, DST)                                                          \
    __builtin_amdgcn_global_load_lds(                                            \
        (const __attribute__((address_space(1))) unsigned*)(const void*)(SRC),   \
        (__attribute__((address_space(3))) unsigned*)(void*)(DST), 16, 0, 0)

__device__ __forceinline__ unsigned short f2bf(float f) {
    unsigned u = __builtin_bit_cast(unsigned, f);
    u += 0x7FFFu + ((u >> 16) & 1u);
    return (unsigned short)(u >> 16);
}
__device__ __forceinline__ float gelu_exact(float v) {
    return 0.5f * v * (1.0f + erff(v * 0.70710678118654752440f));
}

// ---- workspace layout (bytes) ----
constexpr size_t ENCB_OFF = 0;                        // enc bf16: 32*2048*128*2 = 16 MB
constexpr size_t WEF_OFF  = 16777216;                 // WencF frag-major [20][4][128][8]
constexpr size_t W1F_OFF  = WEF_OFF + 163840;         // W1F [4][2][4][128][8]
constexpr size_t W2F_OFF  = W1F_OFF + 65536;          // W2F [2][2][4][64][8]
constexpr size_t FC_OFF   = W2F_OFF + 16384;
constexpr size_t FL_OFF   = FC_OFF + 64;              // flist FCAP u32 (64 KB)

// ================= prep: frag-major bf16 W layouts =================
__global__ void prep_kernel(const float* __restrict__ Wenc, const float* __restrict__ W1,
                            const float* __restrict__ W2,
                            unsigned short* __restrict__ WeF, unsigned short* __restrict__ W1F,
                            unsigned short* __restrict__ W2F)
{
    const int tid = blockIdx.x * blockDim.x + threadIdx.x;
    const int nth = gridDim.x * blockDim.x;
    // WeF: [kc<20][rg<4][n<128][j<8], k = kc*32+rg*8+j
    for (int i = tid; i < 20 * 4 * 128 * 8; i += nth) {
        int j = i & 7, n = (i >> 3) & 127, rg = (i >> 10) & 3, kc = i >> 12;
        int k = kc * 32 + rg * 8 + j;
        WeF[i] = f2bf(Wenc[(size_t)k * kH + n]);
    }
    // W1F: [kc<4][ks<2][rg<4][n<128][j<8], k = kc*64+ks*32+rg*8+j
    for (int i = tid; i < 4 * 2 * 4 * 128 * 8; i += nth) {
        int j = i & 7, n = (i >> 3) & 127, rg = (i >> 10) & 3, ks = (i >> 12) & 1, kc = i >> 13;
        int k = kc * 64 + ks * 32 + rg * 8 + j;
        W1F[i] = f2bf(W1[(size_t)k * kH + n]);
    }
    // W2F: [kc2<2][ks<2][rg<4][n<64][j<8], k = kc2*64+ks*32+rg*8+j
    for (int i = tid; i < 2 * 2 * 4 * 64 * 8; i += nth) {
        int j = i & 7, n = (i >> 3) & 63, rg = (i >> 9) & 3, ks = (i >> 11) & 1, kc2 = i >> 12;
        int k = kc2 * 64 + ks * 32 + rg * 8 + j;
        W2F[i] = f2bf(W2[(size_t)k * 64 + n]);
    }
}

// ================= encoder: bf16 MFMA + LN + GELU (512 thr, 2D wave tile) =================
// 8 waves; wave (wr = w>>1, wc = w&1): rows wr*32..+31, cols wc*64..+63.
constexpr int AP = 40;    // x LDS pitch in ushorts (80B)

__global__ __launch_bounds__(512, 4)
void enc_kernel(const float* __restrict__ x, const unsigned short* __restrict__ WeF,
                const float* __restrict__ benc, const float* __restrict__ gma,
                const float* __restrict__ bta, unsigned short* __restrict__ encb)
{
    __shared__ unsigned short xsh[147 * AP];     // 5880 ush
    __shared__ unsigned short wth[4096];         // frag-major chunk [rg][n][8]
    __shared__ float red[2][128][2];             // LN partials [stat][row][wc]

    const int tid = threadIdx.x, b = blockIdx.y, t0 = blockIdx.x * 128;
    const int l = tid & 63, w = tid >> 6;
    const int wr = w >> 1, wc = w & 1;
    const int cb = l & 15, rg = l >> 4;

    // stage x rows t0..t0+146 (f32 -> bf16)
    const float4* x4 = reinterpret_cast<const float4*>(x + (size_t)b * kS * kI);
    for (int i = tid; i < 147 * 8; i += 512) {
        int r = i >> 3, q = i & 7;
        int gr = t0 + r; if (gr > kS - 1) gr = kS - 1;
        float4 v = x4[gr * 8 + q];
        unsigned short h0 = f2bf(v.x), h1 = f2bf(v.y), h2 = f2bf(v.z), h3 = f2bf(v.w);
        *reinterpret_cast<uint2*>(&xsh[r * AP + q * 4]) =
            make_uint2((unsigned)h0 | ((unsigned)h1 << 16), (unsigned)h2 | ((unsigned)h3 << 16));
    }

    f32x4 acc[2][4];
    #pragma unroll
    for (int mi = 0; mi < 2; ++mi)
        #pragma unroll
        for (int nf = 0; nf < 4; ++nf) acc[mi][nf] = f32x4{0.f, 0.f, 0.f, 0.f};

    for (int kc = 0; kc < 20; ++kc) {            // K = 640 in chunks of 32
        __syncthreads();                         // prior reads done before DMA overwrite
        GLD16(WeF + (size_t)kc * 4096 + w * 512 + l * 8, &wth[w * 512]);
        __syncthreads();                         // DMA drained -> W tile ready
        const int a0o = (wr * 32 + cb + kc) * AP + rg * 8;
        short8 a0 = *reinterpret_cast<const short8*>(&xsh[a0o]);
        short8 a1 = *reinterpret_cast<const short8*>(&xsh[a0o + 16 * AP]);
        #pragma unroll
        for (int nf = 0; nf < 4; ++nf) {
            const int bo = rg * 1024 + (wc * 64 + nf * 16 + cb) * 8;   // frag-major
            short8 bh = *reinterpret_cast<const short8*>(&wth[bo]);
            acc[0][nf] = __builtin_amdgcn_mfma_f32_16x16x32_bf16(a0, bh, acc[0][nf], 0, 0, 0);
            acc[1][nf] = __builtin_amdgcn_mfma_f32_16x16x32_bf16(a1, bh, acc[1][nf], 0, 0, 0);
        }
    }

    // epilogue: C/D col = lane&15, row = (lane>>4)*4 + reg ; LN cross-wave ; GELU ; bf16 store
    float bv[4], gv[4], btv[4];
    #pragma unroll
    for (int nf = 0; nf < 4; ++nf) {
        const int col = wc * 64 + nf * 16 + cb;
        bv[nf] = benc[col]; gv[nf] = gma[col]; btv[nf] = bta[col];
    }
    float h[2][4][4];
    #pragma unroll
    for (int mi = 0; mi < 2; ++mi)
        #pragma unroll
        for (int r = 0; r < 4; ++r) {
            float s = 0.f;
            #pragma unroll
            for (int nf = 0; nf < 4; ++nf) {
                h[mi][r][nf] = acc[mi][nf][r] + bv[nf];
                s += h[mi][r][nf];
            }
            s += __shfl_xor(s, 1); s += __shfl_xor(s, 2);
            s += __shfl_xor(s, 4); s += __shfl_xor(s, 8);
            if (cb == 0) red[0][wr * 32 + mi * 16 + rg * 4 + r][wc] = s;
        }
    __syncthreads();
    #pragma unroll
    for (int mi = 0; mi < 2; ++mi)
        #pragma unroll
        for (int r = 0; r < 4; ++r) {
            const int rl = wr * 32 + mi * 16 + rg * 4 + r;
            const float mu = (red[0][rl][0] + red[0][rl][1]) * (1.f / 128.f);
            float s2 = 0.f;
            #pragma unroll
            for (int nf = 0; nf < 4; ++nf) {
                h[mi][r][nf] -= mu;
                s2 += h[mi][r][nf] * h[mi][r][nf];
            }
            s2 += __shfl_xor(s2, 1); s2 += __shfl_xor(s2, 2);
            s2 += __shfl_xor(s2, 4); s2 += __shfl_xor(s2, 8);
            if (cb == 0) red[1][rl][wc] = s2;
        }
    __syncthreads();
    #pragma unroll
    for (int mi = 0; mi < 2; ++mi)
        #pragma unroll
        for (int r = 0; r < 4; ++r) {
            const int rl = wr * 32 + mi * 16 + rg * 4 + r;
            const int t = t0 + rl;
            const float var = (red[1][rl][0] + red[1][rl][1]) * (1.f / 128.f);
            const float rstd = 1.f / sqrtf(var + kEps);
            if (t < kNwin) {
                unsigned short* dst = encb + ((size_t)(b * kS + t)) * kH;
                #pragma unroll
                for (int nf = 0; nf < 4; ++nf) {
                    float v = gelu_exact(h[mi][r][nf] * rstd * gv[nf] + btv[nf]);
                    dst[wc * 64 + nf * 16 + cb] = f2bf(v);
                }
            }
        }
}

// ================= comparator (512 thr): L1 16r x 64c, L2 16r x 32c =================
// pool (ush): phase1: esh@0 (64*72=4608) | wt1h@4608 (8192) -> 12800
//             phase2: z1h@0 (64*136=8704) | w2h@8704 (4096) -> 12800
//             phase3: z2f f32 @0 (64*68*2=8704 ush)
constexpr int EPP = 72;

__global__ __launch_bounds__(512, 4)
void cmp_kernel(const unsigned short* __restrict__ encb,
                const unsigned short* __restrict__ W1F, const float* __restrict__ b1,
                const unsigned short* __restrict__ W2F, const float* __restrict__ b2,
                const float* __restrict__ W3, const float* __restrict__ b3,
                float* __restrict__ out, int* __restrict__ fcnt, unsigned* __restrict__ flist)
{
    __shared__ __align__(16) unsigned short pool[12800];   // 25.6 KB
    __shared__ float prm[192];

    unsigned short* esh  = pool;
    unsigned short* wt1h = pool + 4608;

    const int tid = threadIdx.x, b = blockIdx.y, t0 = blockIdx.x * 64;
    const int l = tid & 63, w = tid >> 6;
    const int wr = w >> 1, wc = w & 1;
    const int cb = l & 15, rg = l >> 4;

    if (tid < 128) prm[tid] = b1[tid];
    else if (tid < 192) prm[tid] = b2[tid - 128];

    // ---- layer 1: A[t][k] = enc[t + (k<128?0:20)][k&127], K=256 in 4 chunks of 64
    f32x4 acc1[4];
    #pragma unroll
    for (int nf = 0; nf < 4; ++nf) acc1[nf] = f32x4{0.f, 0.f, 0.f, 0.f};

    for (int kc = 0; kc < 4; ++kc) {
        const int ro = (kc < 2) ? 0 : kW, co = (kc & 1) * 64;
        __syncthreads();
        // W1 chunk: 8192 ush = 2 DMA rounds of 8 waves
        GLD16(W1F + (size_t)kc * 8192 + w * 512 + l * 8, &wt1h[w * 512]);
        GLD16(W1F + (size_t)kc * 8192 + 4096 + w * 512 + l * 8, &wt1h[4096 + w * 512]);
        {   // stage enc slice: 64 rows x 64 bf16, raw ush8 copy (512 units)
            const int r = tid >> 3, qq = tid & 7;
            int gr = t0 + ro + r; if (gr > kNwin - 1) gr = kNwin - 1;
            *reinterpret_cast<ush8*>(&esh[r * EPP + qq * 8]) =
                *reinterpret_cast<const ush8*>(encb + ((size_t)(b * kS + gr)) * kH + co + qq * 8);
        }
        __syncthreads();
        #pragma unroll
        for (int ks = 0; ks < 2; ++ks) {
            const int ao = (wr * 16 + cb) * EPP + ks * 32 + rg * 8;
            short8 ah = *reinterpret_cast<const short8*>(&esh[ao]);
            #pragma unroll
            for (int nf = 0; nf < 4; ++nf) {
                const int bo = (ks * 4 + rg) * 1024 + (wc * 64 + nf * 16 + cb) * 8;
                short8 bh = *reinterpret_cast<const short8*>(&wt1h[bo]);
                acc1[nf] = __builtin_amdgcn_mfma_f32_16x16x32_bf16(ah, bh, acc1[nf], 0, 0, 0);
            }
        }
    }
    __syncthreads();     // all es/wt1 reads done; z1 overlays
    unsigned short* z1h = pool;
    unsigned short* w2h = pool + 8704;
    #pragma unroll
    for (int r = 0; r < 4; ++r) {
        const int row = wr * 16 + rg * 4 + r;
        #pragma unroll
        for (int nf = 0; nf < 4; ++nf) {
            const int col = wc * 64 + nf * 16 + cb;
            z1h[row * 136 + col] = f2bf(gelu_exact(acc1[nf][r] + prm[col]));
        }
    }

    // ---- layer 2: K=128 in 2 chunks of 64, N=64; wave tile 16r x 32c
    f32x4 acc2[2];
    #pragma unroll
    for (int nf = 0; nf < 2; ++nf) acc2[nf] = f32x4{0.f, 0.f, 0.f, 0.f};

    for (int kc2 = 0; kc2 < 2; ++kc2) {
        __syncthreads();
        GLD16(W2F + (size_t)kc2 * 4096 + w * 512 + l * 8, &w2h[w * 512]);
        __syncthreads();
        #pragma unroll
        for (int ks = 0; ks < 2; ++ks) {
            const int ao = (wr * 16 + cb) * 136 + kc2 * 64 + ks * 32 + rg * 8;
            short8 ah = *reinterpret_cast<const short8*>(&z1h[ao]);
            #pragma unroll
            for (int nf = 0; nf < 2; ++nf) {
                const int bo = (ks * 4 + rg) * 512 + (wc * 32 + nf * 16 + cb) * 8;
                short8 bh = *reinterpret_cast<const short8*>(&w2h[bo]);
                acc2[nf] = __builtin_amdgcn_mfma_f32_16x16x32_bf16(ah, bh, acc2[nf], 0, 0, 0);
            }
        }
    }
    __syncthreads();     // z1/w2 reads done; z2f overlays
    float* z2f = reinterpret_cast<float*>(pool);   // 64 x 68 f32
    #pragma unroll
    for (int r = 0; r < 4; ++r) {
        const int row = wr * 16 + rg * 4 + r;
        #pragma unroll
        for (int nf = 0; nf < 2; ++nf) {
            const int col = wc * 32 + nf * 16 + cb;
            z2f[row * 68 + col] = gelu_exact(acc2[nf][r] + prm[128 + col]);
        }
    }
    __syncthreads();

    // ---- layer 3: dot + sigmoid; flag borderline
    if (tid < 64) {
        const int t = t0 + tid;
        if (t < kT) {
            float s = 0.f;
            #pragma unroll 8
            for (int k = 0; k < 64; ++k) s = fmaf(z2f[tid * 68 + k], W3[k], s);
            const float p = 1.f / (1.f + expf(-(s + b3[0])));
            out[(size_t)b * kS + t + kW] = p;
            out[(size_t)kB * kS + (size_t)b * kS + t + kW] = (p > 0.5f) ? 1.f : 0.f;
            if (fabsf(p - 0.5f) < kMargin) {
                int idx = atomicAdd(fcnt, 1);
                if (idx < FCAP) flist[idx] = ((unsigned)b << 16) | (unsigned)t;
            }
        }
    }
}

// ================= fix2: full fp32 recompute per flagged position =================
__global__ __launch_bounds__(256, 4)
void fix2_kernel(const float* __restrict__ x, const float* __restrict__ Wenc,
                 const float* __restrict__ benc, const float* __restrict__ gma,
                 const float* __restrict__ bta, const float* __restrict__ W1,
                 const float* __restrict__ b1, const float* __restrict__ W2,
                 const float* __restrict__ b2, const float* __restrict__ W3,
                 const float* __restrict__ b3, const int* __restrict__ fcnt,
                 const unsigned* __restrict__ flist, float* __restrict__ out)
{
    __shared__ float xw[1280];
    __shared__ float es[256];
    __shared__ float z1s[128];
    __shared__ float z2s[64];
    __shared__ float wred[4];

    const int tid = threadIdx.x;
    int n = *fcnt; if (n > FCAP) n = FCAP;

    for (int i = blockIdx.x; i < n; i += gridDim.x) {
        const unsigned e = flist[i];
        const int b = (int)(e >> 16), t = (int)(e & 0xFFFF);
        __syncthreads();
        for (int j = tid; j < 320; j += 256) {
            int r = (j >= 160) ? 1 : 0, u = j - r * 160;
            const float4 v = *reinterpret_cast<const float4*>(
                x + ((size_t)b * kS + t + r * kW) * kI + u * 4);
            *reinterpret_cast<float4*>(&xw[r * 640 + u * 4]) = v;
        }
        __syncthreads();
        const int r = tid >> 7, c = tid & 127;
        float h = 0.f;
        const float* xr = &xw[r * 640];
        #pragma unroll 16
        for (int k = 0; k < 640; ++k) h = fmaf(xr[k], Wenc[(size_t)k * kH + c], h);
        h += benc[c];
        float s = h;
        #pragma unroll
        for (int m = 1; m < 64; m <<= 1) s += __shfl_xor(s, m, 64);
        if ((tid & 63) == 0) wred[tid >> 6] = s;
        __syncthreads();
        const float mu = (wred[r * 2] + wred[r * 2 + 1]) * (1.f / 128.f);
        const float d = h - mu;
        float s2 = d * d;
        #pragma unroll
        for (int m = 1; m < 64; m <<= 1) s2 += __shfl_xor(s2, m, 64);
        __syncthreads();
        if ((tid & 63) == 0) wred[tid >> 6] = s2;
        __syncthreads();
        const float var = (wred[r * 2] + wred[r * 2 + 1]) * (1.f / 128.f);
        es[tid] = gelu_exact(d * (1.f / sqrtf(var + kEps)) * gma[c] + bta[c]);
        __syncthreads();
        if (tid < kH) {
            float z = 0.f;
            #pragma unroll 16
            for (int k = 0; k < 256; ++k) z = fmaf(es[k], W1[(size_t)k * kH + tid], z);
            z1s[tid] = gelu_exact(z + b1[tid]);
        }
        __syncthreads();
        if (tid < 64) {
            float z = 0.f;
            #pragma unroll 16
            for (int k = 0; k < kH; ++k) z = fmaf(z1s[k], W2[(size_t)k * 64 + tid], z);
            z2s[tid] = gelu_exact(z + b2[tid]);
        }
        __syncthreads();
        if (tid < 64) {
            float s3 = z2s[tid] * W3[tid];
            #pragma unroll
            for (int m = 1; m < 64; m <<= 1) s3 += __shfl_xor(s3, m, 64);
            if (tid == 0) {
                const float p = 1.f / (1.f + expf(-(s3 + b3[0])));
                out[(size_t)b * kS + t + kW] = p;
                out[(size_t)kB * kS + (size_t)b * kS + t + kW] = (p > 0.5f) ? 1.f : 0.f;
            }
        }
        __syncthreads();
    }
}

}  // namespace

extern "C" void kernel_launch(void* const* d_in, const int* in_sizes, int n_in,
                              void* d_out, int out_size, void* d_ws, size_t ws_size,
                              hipStream_t stream)
{
    const float* x    = (const float*)d_in[0];
    const float* Wenc = (const float*)d_in[1];
    const float* benc = (const float*)d_in[2];
    const float* gma  = (const float*)d_in[3];
    const float* bta  = (const float*)d_in[4];
    const float* W1   = (const float*)d_in[5];
    const float* b1   = (const float*)d_in[6];
    const float* W2   = (const float*)d_in[7];
    const float* b2   = (const float*)d_in[8];
    const float* W3   = (const float*)d_in[9];
    const float* b3   = (const float*)d_in[10];
    float* out = (float*)d_out;

    char* ws = (char*)d_ws;
    unsigned short* encb  = (unsigned short*)(ws + ENCB_OFF);
    unsigned short* WeF   = (unsigned short*)(ws + WEF_OFF);
    unsigned short* W1F   = (unsigned short*)(ws + W1F_OFF);
    unsigned short* W2F   = (unsigned short*)(ws + W2F_OFF);
    int* fcnt             = (int*)(ws + FC_OFF);
    unsigned* flist       = (unsigned*)(ws + FL_OFF);

    hipMemsetAsync(d_out, 0, (size_t)out_size * sizeof(float), stream);
    hipMemsetAsync(fcnt, 0, 64, stream);

    prep_kernel<<<256, 256, 0, stream>>>(Wenc, W1, W2, WeF, W1F, W2F);
    enc_kernel<<<dim3(16, kB), 512, 0, stream>>>(x, WeF, benc, gma, bta, encb);
    cmp_kernel<<<dim3(32, kB), 512, 0, stream>>>(encb, W1F, b1, W2F, b2, W3, b3,
                                                 out, fcnt, flist);
    fix2_kernel<<<4096, 256, 0, stream>>>(x, Wenc, benc, gma, bta, W1, b1, W2, b2, W3, b3,
                                          fcnt, flist, out);
}

// Round 18
// 168.486 us; speedup vs baseline: 2.0827x; 2.0827x over previous
//
#include <hip/hip_runtime.h>
#include <hip/hip_bf16.h>
#include <math.h>

namespace {

constexpr int kB = 32;
constexpr int kS = 2048;
constexpr int kI = 32;
constexpr int kW = 20;
constexpr int kH = 128;
constexpr int kNwin = kS - kW + 1;   // 2029
constexpr int kT = kS - 2 * kW;      // 2008
constexpr float kEps = 1e-5f;
constexpr int FCAP = 16384;
constexpr float kMargin = 3e-3f;     // fp16 1-pass p-error bound ~5e-4 << 3e-3

typedef __attribute__((ext_vector_type(8))) _Float16 half8;       // 8 f16 (4 VGPR)
typedef __attribute__((ext_vector_type(8))) unsigned short ush8;  // 16B unit
typedef __attribute__((ext_vector_type(4))) float f32x4;

// async global->LDS DMA, 16B per lane; dest = uniform base + lane*16 (linear)
#define GLD16(SRC, DST)                                                          \
    __builtin_amdgcn_global_load_lds(                                            \
        (const __attribute__((address_space(1))) unsigned*)(const void*)(SRC),   \
        (__attribute__((address_space(3))) unsigned*)(void*)(DST), 16, 0, 0)

__device__ __forceinline__ unsigned short f2h(float f) {          // RNE f32->f16
    _Float16 h = (_Float16)f;
    return __builtin_bit_cast(unsigned short, h);
}
__device__ __forceinline__ float gelu_exact(float v) {
    return 0.5f * v * (1.0f + erff(v * 0.70710678118654752440f));
}

// ---- workspace layout (bytes) ----
constexpr size_t ENCB_OFF = 0;                        // enc f16: 32*2048*128*2 = 16 MB
constexpr size_t WEF_OFF  = 16777216;                 // WencF frag-major [20][4][128][8]
constexpr size_t W1F_OFF  = WEF_OFF + 163840;         // W1F [4][2][4][128][8]
constexpr size_t W2F_OFF  = W1F_OFF + 65536;          // W2F [2][2][4][64][8]
constexpr size_t FC_OFF   = W2F_OFF + 16384;
constexpr size_t FL_OFF   = FC_OFF + 64;              // flist FCAP u32 (64 KB)

// ================= prep: frag-major f16 W layouts =================
__global__ void prep_kernel(const float* __restrict__ Wenc, const float* __restrict__ W1,
                            const float* __restrict__ W2,
                            unsigned short* __restrict__ WeF, unsigned short* __restrict__ W1F,
                            unsigned short* __restrict__ W2F)
{
    const int tid = blockIdx.x * blockDim.x + threadIdx.x;
    const int nth = gridDim.x * blockDim.x;
    // WeF: [kc<20][rg<4][n<128][j<8], k = kc*32+rg*8+j
    for (int i = tid; i < 20 * 4 * 128 * 8; i += nth) {
        int j = i & 7, n = (i >> 3) & 127, rg = (i >> 10) & 3, kc = i >> 12;
        int k = kc * 32 + rg * 8 + j;
        WeF[i] = f2h(Wenc[(size_t)k * kH + n]);
    }
    // W1F: [kc<4][ks<2][rg<4][n<128][j<8], k = kc*64+ks*32+rg*8+j
    for (int i = tid; i < 4 * 2 * 4 * 128 * 8; i += nth) {
        int j = i & 7, n = (i >> 3) & 127, rg = (i >> 10) & 3, ks = (i >> 12) & 1, kc = i >> 13;
        int k = kc * 64 + ks * 32 + rg * 8 + j;
        W1F[i] = f2h(W1[(size_t)k * kH + n]);
    }
    // W2F: [kc2<2][ks<2][rg<4][n<64][j<8], k = kc2*64+ks*32+rg*8+j
    for (int i = tid; i < 2 * 2 * 4 * 64 * 8; i += nth) {
        int j = i & 7, n = (i >> 3) & 63, rg = (i >> 9) & 3, ks = (i >> 11) & 1, kc2 = i >> 12;
        int k = kc2 * 64 + ks * 32 + rg * 8 + j;
        W2F[i] = f2h(W2[(size_t)k * 64 + n]);
    }
}

// ================= encoder: f16 MFMA + LN + GELU (512 thr, 2D wave tile) =================
// 8 waves; wave (wr = w>>1, wc = w&1): rows wr*32..+31, cols wc*64..+63.
constexpr int AP = 40;    // x LDS pitch in ushorts (80B)

__global__ __launch_bounds__(512, 4)
void enc_kernel(const float* __restrict__ x, const unsigned short* __restrict__ WeF,
                const float* __restrict__ benc, const float* __restrict__ gma,
                const float* __restrict__ bta, unsigned short* __restrict__ encb)
{
    __shared__ unsigned short xsh[147 * AP];     // 5880 ush
    __shared__ unsigned short wth[4096];         // frag-major chunk [rg][n][8]
    __shared__ float red[2][128][2];             // LN partials [stat][row][wc]

    const int tid = threadIdx.x, b = blockIdx.y, t0 = blockIdx.x * 128;
    const int l = tid & 63, w = tid >> 6;
    const int wr = w >> 1, wc = w & 1;
    const int cb = l & 15, rg = l >> 4;

    // stage x rows t0..t0+146 (f32 -> f16)
    const float4* x4 = reinterpret_cast<const float4*>(x + (size_t)b * kS * kI);
    for (int i = tid; i < 147 * 8; i += 512) {
        int r = i >> 3, q = i & 7;
        int gr = t0 + r; if (gr > kS - 1) gr = kS - 1;
        float4 v = x4[gr * 8 + q];
        unsigned short h0 = f2h(v.x), h1 = f2h(v.y), h2 = f2h(v.z), h3 = f2h(v.w);
        *reinterpret_cast<uint2*>(&xsh[r * AP + q * 4]) =
            make_uint2((unsigned)h0 | ((unsigned)h1 << 16), (unsigned)h2 | ((unsigned)h3 << 16));
    }

    f32x4 acc[2][4];
    #pragma unroll
    for (int mi = 0; mi < 2; ++mi)
        #pragma unroll
        for (int nf = 0; nf < 4; ++nf) acc[mi][nf] = f32x4{0.f, 0.f, 0.f, 0.f};

    for (int kc = 0; kc < 20; ++kc) {            // K = 640 in chunks of 32
        __syncthreads();                         // prior reads done before DMA overwrite
        GLD16(WeF + (size_t)kc * 4096 + w * 512 + l * 8, &wth[w * 512]);
        __syncthreads();                         // DMA drained -> W tile ready
        const int a0o = (wr * 32 + cb + kc) * AP + rg * 8;
        half8 a0 = *reinterpret_cast<const half8*>(&xsh[a0o]);
        half8 a1 = *reinterpret_cast<const half8*>(&xsh[a0o + 16 * AP]);
        #pragma unroll
        for (int nf = 0; nf < 4; ++nf) {
            const int bo = rg * 1024 + (wc * 64 + nf * 16 + cb) * 8;   // frag-major
            half8 bh = *reinterpret_cast<const half8*>(&wth[bo]);
            acc[0][nf] = __builtin_amdgcn_mfma_f32_16x16x32_f16(a0, bh, acc[0][nf], 0, 0, 0);
            acc[1][nf] = __builtin_amdgcn_mfma_f32_16x16x32_f16(a1, bh, acc[1][nf], 0, 0, 0);
        }
    }

    // epilogue: C/D col = lane&15, row = (lane>>4)*4 + reg ; LN cross-wave ; GELU ; f16 store
    float bv[4], gv[4], btv[4];
    #pragma unroll
    for (int nf = 0; nf < 4; ++nf) {
        const int col = wc * 64 + nf * 16 + cb;
        bv[nf] = benc[col]; gv[nf] = gma[col]; btv[nf] = bta[col];
    }
    float h[2][4][4];
    #pragma unroll
    for (int mi = 0; mi < 2; ++mi)
        #pragma unroll
        for (int r = 0; r < 4; ++r) {
            float s = 0.f;
            #pragma unroll
            for (int nf = 0; nf < 4; ++nf) {
                h[mi][r][nf] = acc[mi][nf][r] + bv[nf];
                s += h[mi][r][nf];
            }
            s += __shfl_xor(s, 1); s += __shfl_xor(s, 2);
            s += __shfl_xor(s, 4); s += __shfl_xor(s, 8);
            if (cb == 0) red[0][wr * 32 + mi * 16 + rg * 4 + r][wc] = s;
        }
    __syncthreads();
    #pragma unroll
    for (int mi = 0; mi < 2; ++mi)
        #pragma unroll
        for (int r = 0; r < 4; ++r) {
            const int rl = wr * 32 + mi * 16 + rg * 4 + r;
            const float mu = (red[0][rl][0] + red[0][rl][1]) * (1.f / 128.f);
            float s2 = 0.f;
            #pragma unroll
            for (int nf = 0; nf < 4; ++nf) {
                h[mi][r][nf] -= mu;
                s2 += h[mi][r][nf] * h[mi][r][nf];
            }
            s2 += __shfl_xor(s2, 1); s2 += __shfl_xor(s2, 2);
            s2 += __shfl_xor(s2, 4); s2 += __shfl_xor(s2, 8);
            if (cb == 0) red[1][rl][wc] = s2;
        }
    __syncthreads();
    #pragma unroll
    for (int mi = 0; mi < 2; ++mi)
        #pragma unroll
        for (int r = 0; r < 4; ++r) {
            const int rl = wr * 32 + mi * 16 + rg * 4 + r;
            const int t = t0 + rl;
            const float var = (red[1][rl][0] + red[1][rl][1]) * (1.f / 128.f);
            const float rstd = 1.f / sqrtf(var + kEps);
            if (t < kNwin) {
                unsigned short* dst = encb + ((size_t)(b * kS + t)) * kH;
                #pragma unroll
                for (int nf = 0; nf < 4; ++nf) {
                    float v = gelu_exact(h[mi][r][nf] * rstd * gv[nf] + btv[nf]);
                    dst[wc * 64 + nf * 16 + cb] = f2h(v);
                }
            }
        }
}

// ================= comparator (512 thr): L1 16r x 64c, L2 16r x 32c =================
// pool (ush): phase1: esh@0 (64*72=4608) | wt1h@4608 (8192) -> 12800
//             phase2: z1h@0 (64*136=8704) | w2h@8704 (4096) -> 12800
//             phase3: z2f f32 @0 (64*68*2=8704 ush)
constexpr int EPP = 72;

__global__ __launch_bounds__(512, 4)
void cmp_kernel(const unsigned short* __restrict__ encb,
                const unsigned short* __restrict__ W1F, const float* __restrict__ b1,
                const unsigned short* __restrict__ W2F, const float* __restrict__ b2,
                const float* __restrict__ W3, const float* __restrict__ b3,
                float* __restrict__ out, int* __restrict__ fcnt, unsigned* __restrict__ flist)
{
    __shared__ __align__(16) unsigned short pool[12800];   // 25.6 KB
    __shared__ float prm[192];

    unsigned short* esh  = pool;
    unsigned short* wt1h = pool + 4608;

    const int tid = threadIdx.x, b = blockIdx.y, t0 = blockIdx.x * 64;
    const int l = tid & 63, w = tid >> 6;
    const int wr = w >> 1, wc = w & 1;
    const int cb = l & 15, rg = l >> 4;

    if (tid < 128) prm[tid] = b1[tid];
    else if (tid < 192) prm[tid] = b2[tid - 128];

    // ---- layer 1: A[t][k] = enc[t + (k<128?0:20)][k&127], K=256 in 4 chunks of 64
    f32x4 acc1[4];
    #pragma unroll
    for (int nf = 0; nf < 4; ++nf) acc1[nf] = f32x4{0.f, 0.f, 0.f, 0.f};

    for (int kc = 0; kc < 4; ++kc) {
        const int ro = (kc < 2) ? 0 : kW, co = (kc & 1) * 64;
        __syncthreads();
        // W1 chunk: 8192 ush = 2 DMA rounds of 8 waves
        GLD16(W1F + (size_t)kc * 8192 + w * 512 + l * 8, &wt1h[w * 512]);
        GLD16(W1F + (size_t)kc * 8192 + 4096 + w * 512 + l * 8, &wt1h[4096 + w * 512]);
        {   // stage enc slice: 64 rows x 64 f16, raw ush8 copy (512 units)
            const int r = tid >> 3, qq = tid & 7;
            int gr = t0 + ro + r; if (gr > kNwin - 1) gr = kNwin - 1;
            *reinterpret_cast<ush8*>(&esh[r * EPP + qq * 8]) =
                *reinterpret_cast<const ush8*>(encb + ((size_t)(b * kS + gr)) * kH + co + qq * 8);
        }
        __syncthreads();
        #pragma unroll
        for (int ks = 0; ks < 2; ++ks) {
            const int ao = (wr * 16 + cb) * EPP + ks * 32 + rg * 8;
            half8 ah = *reinterpret_cast<const half8*>(&esh[ao]);
            #pragma unroll
            for (int nf = 0; nf < 4; ++nf) {
                const int bo = (ks * 4 + rg) * 1024 + (wc * 64 + nf * 16 + cb) * 8;
                half8 bh = *reinterpret_cast<const half8*>(&wt1h[bo]);
                acc1[nf] = __builtin_amdgcn_mfma_f32_16x16x32_f16(ah, bh, acc1[nf], 0, 0, 0);
            }
        }
    }
    __syncthreads();     // all es/wt1 reads done; z1 overlays
    unsigned short* z1h = pool;
    unsigned short* w2h = pool + 8704;
    #pragma unroll
    for (int r = 0; r < 4; ++r) {
        const int row = wr * 16 + rg * 4 + r;
        #pragma unroll
        for (int nf = 0; nf < 4; ++nf) {
            const int col = wc * 64 + nf * 16 + cb;
            z1h[row * 136 + col] = f2h(gelu_exact(acc1[nf][r] + prm[col]));
        }
    }

    // ---- layer 2: K=128 in 2 chunks of 64, N=64; wave tile 16r x 32c
    f32x4 acc2[2];
    #pragma unroll
    for (int nf = 0; nf < 2; ++nf) acc2[nf] = f32x4{0.f, 0.f, 0.f, 0.f};

    for (int kc2 = 0; kc2 < 2; ++kc2) {
        __syncthreads();
        GLD16(W2F + (size_t)kc2 * 4096 + w * 512 + l * 8, &w2h[w * 512]);
        __syncthreads();
        #pragma unroll
        for (int ks = 0; ks < 2; ++ks) {
            const int ao = (wr * 16 + cb) * 136 + kc2 * 64 + ks * 32 + rg * 8;
            half8 ah = *reinterpret_cast<const half8*>(&z1h[ao]);
            #pragma unroll
            for (int nf = 0; nf < 2; ++nf) {
                const int bo = (ks * 4 + rg) * 512 + (wc * 32 + nf * 16 + cb) * 8;
                half8 bh = *reinterpret_cast<const half8*>(&w2h[bo]);
                acc2[nf] = __builtin_amdgcn_mfma_f32_16x16x32_f16(ah, bh, acc2[nf], 0, 0, 0);
            }
        }
    }
    __syncthreads();     // z1/w2 reads done; z2f overlays
    float* z2f = reinterpret_cast<float*>(pool);   // 64 x 68 f32
    #pragma unroll
    for (int r = 0; r < 4; ++r) {
        const int row = wr * 16 + rg * 4 + r;
        #pragma unroll
        for (int nf = 0; nf < 2; ++nf) {
            const int col = wc * 32 + nf * 16 + cb;
            z2f[row * 68 + col] = gelu_exact(acc2[nf][r] + prm[128 + col]);
        }
    }
    __syncthreads();

    // ---- layer 3: dot + sigmoid; flag borderline
    if (tid < 64) {
        const int t = t0 + tid;
        if (t < kT) {
            float s = 0.f;
            #pragma unroll 8
            for (int k = 0; k < 64; ++k) s = fmaf(z2f[tid * 68 + k], W3[k], s);
            const float p = 1.f / (1.f + expf(-(s + b3[0])));
            out[(size_t)b * kS + t + kW] = p;
            out[(size_t)kB * kS + (size_t)b * kS + t + kW] = (p > 0.5f) ? 1.f : 0.f;
            if (fabsf(p - 0.5f) < kMargin) {
                int idx = atomicAdd(fcnt, 1);
                if (idx < FCAP) flist[idx] = ((unsigned)b << 16) | (unsigned)t;
            }
        }
    }
}

// ================= fix2: full fp32 recompute per flagged position =================
__global__ __launch_bounds__(256, 4)
void fix2_kernel(const float* __restrict__ x, const float* __restrict__ Wenc,
                 const float* __restrict__ benc, const float* __restrict__ gma,
                 const float* __restrict__ bta, const float* __restrict__ W1,
                 const float* __restrict__ b1, const float* __restrict__ W2,
                 const float* __restrict__ b2, const float* __restrict__ W3,
                 const float* __restrict__ b3, const int* __restrict__ fcnt,
                 const unsigned* __restrict__ flist, float* __restrict__ out)
{
    __shared__ float xw[1280];
    __shared__ float es[256];
    __shared__ float z1s[128];
    __shared__ float z2s[64];
    __shared__ float wred[4];

    const int tid = threadIdx.x;
    int n = *fcnt; if (n > FCAP) n = FCAP;

    for (int i = blockIdx.x; i < n; i += gridDim.x) {
        const unsigned e = flist[i];
        const int b = (int)(e >> 16), t = (int)(e & 0xFFFF);
        __syncthreads();
        for (int j = tid; j < 320; j += 256) {
            int r = (j >= 160) ? 1 : 0, u = j - r * 160;
            const float4 v = *reinterpret_cast<const float4*>(
                x + ((size_t)b * kS + t + r * kW) * kI + u * 4);
            *reinterpret_cast<float4*>(&xw[r * 640 + u * 4]) = v;
        }
        __syncthreads();
        const int r = tid >> 7, c = tid & 127;
        float h = 0.f;
        const float* xr = &xw[r * 640];
        #pragma unroll 16
        for (int k = 0; k < 640; ++k) h = fmaf(xr[k], Wenc[(size_t)k * kH + c], h);
        h += benc[c];
        float s = h;
        #pragma unroll
        for (int m = 1; m < 64; m <<= 1) s += __shfl_xor(s, m, 64);
        if ((tid & 63) == 0) wred[tid >> 6] = s;
        __syncthreads();
        const float mu = (wred[r * 2] + wred[r * 2 + 1]) * (1.f / 128.f);
        const float d = h - mu;
        float s2 = d * d;
        #pragma unroll
        for (int m = 1; m < 64; m <<= 1) s2 += __shfl_xor(s2, m, 64);
        __syncthreads();
        if ((tid & 63) == 0) wred[tid >> 6] = s2;
        __syncthreads();
        const float var = (wred[r * 2] + wred[r * 2 + 1]) * (1.f / 128.f);
        es[tid] = gelu_exact(d * (1.f / sqrtf(var + kEps)) * gma[c] + bta[c]);
        __syncthreads();
        if (tid < kH) {
            float z = 0.f;
            #pragma unroll 16
            for (int k = 0; k < 256; ++k) z = fmaf(es[k], W1[(size_t)k * kH + tid], z);
            z1s[tid] = gelu_exact(z + b1[tid]);
        }
        __syncthreads();
        if (tid < 64) {
            float z = 0.f;
            #pragma unroll 16
            for (int k = 0; k < kH; ++k) z = fmaf(z1s[k], W2[(size_t)k * 64 + tid], z);
            z2s[tid] = gelu_exact(z + b2[tid]);
        }
        __syncthreads();
        if (tid < 64) {
            float s3 = z2s[tid] * W3[tid];
            #pragma unroll
            for (int m = 1; m < 64; m <<= 1) s3 += __shfl_xor(s3, m, 64);
            if (tid == 0) {
                const float p = 1.f / (1.f + expf(-(s3 + b3[0])));
                out[(size_t)b * kS + t + kW] = p;
                out[(size_t)kB * kS + (size_t)b * kS + t + kW] = (p > 0.5f) ? 1.f : 0.f;
            }
        }
        __syncthreads();
    }
}

}  // namespace

extern "C" void kernel_launch(void* const* d_in, const int* in_sizes, int n_in,
                              void* d_out, int out_size, void* d_ws, size_t ws_size,
                              hipStream_t stream)
{
    const float* x    = (const float*)d_in[0];
    const float* Wenc = (const float*)d_in[1];
    const float* benc = (const float*)d_in[2];
    const float* gma  = (const float*)d_in[3];
    const float* bta  = (const float*)d_in[4];
    const float* W1   = (const float*)d_in[5];
    const float* b1   = (const float*)d_in[6];
    const float* W2   = (const float*)d_in[7];
    const float* b2   = (const float*)d_in[8];
    const float* W3   = (const float*)d_in[9];
    const float* b3   = (const float*)d_in[10];
    float* out = (float*)d_out;

    char* ws = (char*)d_ws;
    unsigned short* encb  = (unsigned short*)(ws + ENCB_OFF);
    unsigned short* WeF   = (unsigned short*)(ws + WEF_OFF);
    unsigned short* W1F   = (unsigned short*)(ws + W1F_OFF);
    unsigned short* W2F   = (unsigned short*)(ws + W2F_OFF);
    int* fcnt             = (int*)(ws + FC_OFF);
    unsigned* flist       = (unsigned*)(ws + FL_OFF);

    hipMemsetAsync(d_out, 0, (size_t)out_size * sizeof(float), stream);
    hipMemsetAsync(fcnt, 0, 64, stream);

    prep_kernel<<<256, 256, 0, stream>>>(Wenc, W1, W2, WeF, W1F, W2F);
    enc_kernel<<<dim3(16, kB), 512, 0, stream>>>(x, WeF, benc, gma, bta, encb);
    cmp_kernel<<<dim3(32, kB), 512, 0, stream>>>(encb, W1F, b1, W2F, b2, W3, b3,
                                                 out, fcnt, flist);
    fix2_kernel<<<4096, 256, 0, stream>>>(x, Wenc, benc, gma, bta, W1, b1, W2, b2, W3, b3,
                                          fcnt, flist, out);
}

// Round 19
// 135.851 us; speedup vs baseline: 2.5831x; 1.2402x over previous
//
#include <hip/hip_runtime.h>
#include <hip/hip_bf16.h>
#include <math.h>

namespace {

constexpr int kB = 32;
constexpr int kS = 2048;
constexpr int kI = 32;
constexpr int kW = 20;
constexpr int kH = 128;
constexpr int kNwin = kS - kW + 1;   // 2029
constexpr int kT = kS - 2 * kW;      // 2008
constexpr float kEps = 1e-5f;
constexpr int FCAP = 16384;
constexpr float kMargin = 3e-3f;     // fp16 1-pass p-error bound ~5e-4 << 3e-3

typedef __attribute__((ext_vector_type(8))) _Float16 half8;       // 8 f16 (4 VGPR)
typedef __attribute__((ext_vector_type(8))) unsigned short ush8;  // 16B unit
typedef __attribute__((ext_vector_type(4))) float f32x4;

// async global->LDS DMA, 16B per lane; dest = uniform base + lane*16 (linear)
#define GLD16(SRC, DST)                                                          \
    __builtin_amdgcn_global_load_lds(                                            \
        (const __attribute__((address_space(1))) unsigned*)(const void*)(SRC),   \
        (__attribute__((address_space(3))) unsigned*)(void*)(DST), 16, 0, 0)

__device__ __forceinline__ unsigned short f2h(float f) {          // RNE f32->f16
    _Float16 h = (_Float16)f;
    return __builtin_bit_cast(unsigned short, h);
}
__device__ __forceinline__ float gelu_exact(float v) {
    return 0.5f * v * (1.0f + erff(v * 0.70710678118654752440f));
}

// ---- workspace layout (bytes) ----
constexpr size_t ENCB_OFF = 0;                        // enc f16: 32*2048*128*2 = 16 MB
constexpr size_t WEF_OFF  = 16777216;                 // WencF frag-major [20][4][128][8]
constexpr size_t W1F_OFF  = WEF_OFF + 163840;         // W1F [4][2][4][128][8]
constexpr size_t W2F_OFF  = W1F_OFF + 65536;          // W2F [2][2][4][64][8]
constexpr size_t FC_OFF   = W2F_OFF + 16384;
constexpr size_t FL_OFF   = FC_OFF + 64;              // flist FCAP u32 (64 KB)

// ================= prep: frag-major f16 W layouts =================
__global__ void prep_kernel(const float* __restrict__ Wenc, const float* __restrict__ W1,
                            const float* __restrict__ W2,
                            unsigned short* __restrict__ WeF, unsigned short* __restrict__ W1F,
                            unsigned short* __restrict__ W2F)
{
    const int tid = blockIdx.x * blockDim.x + threadIdx.x;
    const int nth = gridDim.x * blockDim.x;
    for (int i = tid; i < 20 * 4 * 128 * 8; i += nth) {
        int j = i & 7, n = (i >> 3) & 127, rg = (i >> 10) & 3, kc = i >> 12;
        int k = kc * 32 + rg * 8 + j;
        WeF[i] = f2h(Wenc[(size_t)k * kH + n]);
    }
    for (int i = tid; i < 4 * 2 * 4 * 128 * 8; i += nth) {
        int j = i & 7, n = (i >> 3) & 127, rg = (i >> 10) & 3, ks = (i >> 12) & 1, kc = i >> 13;
        int k = kc * 64 + ks * 32 + rg * 8 + j;
        W1F[i] = f2h(W1[(size_t)k * kH + n]);
    }
    for (int i = tid; i < 2 * 2 * 4 * 64 * 8; i += nth) {
        int j = i & 7, n = (i >> 3) & 63, rg = (i >> 9) & 3, ks = (i >> 11) & 1, kc2 = i >> 12;
        int k = kc2 * 64 + ks * 32 + rg * 8 + j;
        W2F[i] = f2h(W2[(size_t)k * 64 + n]);
    }
}

// ================= encoder: f16 MFMA + LN + GELU (512 thr, 2D wave tile) =================
constexpr int AP = 40;    // x LDS pitch in ushorts (80B)

__global__ __launch_bounds__(512, 4)
void enc_kernel(const float* __restrict__ x, const unsigned short* __restrict__ WeF,
                const float* __restrict__ benc, const float* __restrict__ gma,
                const float* __restrict__ bta, unsigned short* __restrict__ encb)
{
    __shared__ unsigned short xsh[147 * AP];
    __shared__ unsigned short wth[4096];
    __shared__ float red[2][128][2];

    const int tid = threadIdx.x, b = blockIdx.y, t0 = blockIdx.x * 128;
    const int l = tid & 63, w = tid >> 6;
    const int wr = w >> 1, wc = w & 1;
    const int cb = l & 15, rg = l >> 4;

    const float4* x4 = reinterpret_cast<const float4*>(x + (size_t)b * kS * kI);
    for (int i = tid; i < 147 * 8; i += 512) {
        int r = i >> 3, q = i & 7;
        int gr = t0 + r; if (gr > kS - 1) gr = kS - 1;
        float4 v = x4[gr * 8 + q];
        unsigned short h0 = f2h(v.x), h1 = f2h(v.y), h2 = f2h(v.z), h3 = f2h(v.w);
        *reinterpret_cast<uint2*>(&xsh[r * AP + q * 4]) =
            make_uint2((unsigned)h0 | ((unsigned)h1 << 16), (unsigned)h2 | ((unsigned)h3 << 16));
    }

    f32x4 acc[2][4];
    #pragma unroll
    for (int mi = 0; mi < 2; ++mi)
        #pragma unroll
        for (int nf = 0; nf < 4; ++nf) acc[mi][nf] = f32x4{0.f, 0.f, 0.f, 0.f};

    for (int kc = 0; kc < 20; ++kc) {
        __syncthreads();
        GLD16(WeF + (size_t)kc * 4096 + w * 512 + l * 8, &wth[w * 512]);
        __syncthreads();
        const int a0o = (wr * 32 + cb + kc) * AP + rg * 8;
        half8 a0 = *reinterpret_cast<const half8*>(&xsh[a0o]);
        half8 a1 = *reinterpret_cast<const half8*>(&xsh[a0o + 16 * AP]);
        #pragma unroll
        for (int nf = 0; nf < 4; ++nf) {
            const int bo = rg * 1024 + (wc * 64 + nf * 16 + cb) * 8;
            half8 bh = *reinterpret_cast<const half8*>(&wth[bo]);
            acc[0][nf] = __builtin_amdgcn_mfma_f32_16x16x32_f16(a0, bh, acc[0][nf], 0, 0, 0);
            acc[1][nf] = __builtin_amdgcn_mfma_f32_16x16x32_f16(a1, bh, acc[1][nf], 0, 0, 0);
        }
    }

    float bv[4], gv[4], btv[4];
    #pragma unroll
    for (int nf = 0; nf < 4; ++nf) {
        const int col = wc * 64 + nf * 16 + cb;
        bv[nf] = benc[col]; gv[nf] = gma[col]; btv[nf] = bta[col];
    }
    float h[2][4][4];
    #pragma unroll
    for (int mi = 0; mi < 2; ++mi)
        #pragma unroll
        for (int r = 0; r < 4; ++r) {
            float s = 0.f;
            #pragma unroll
            for (int nf = 0; nf < 4; ++nf) {
                h[mi][r][nf] = acc[mi][nf][r] + bv[nf];
                s += h[mi][r][nf];
            }
            s += __shfl_xor(s, 1); s += __shfl_xor(s, 2);
            s += __shfl_xor(s, 4); s += __shfl_xor(s, 8);
            if (cb == 0) red[0][wr * 32 + mi * 16 + rg * 4 + r][wc] = s;
        }
    __syncthreads();
    #pragma unroll
    for (int mi = 0; mi < 2; ++mi)
        #pragma unroll
        for (int r = 0; r < 4; ++r) {
            const int rl = wr * 32 + mi * 16 + rg * 4 + r;
            const float mu = (red[0][rl][0] + red[0][rl][1]) * (1.f / 128.f);
            float s2 = 0.f;
            #pragma unroll
            for (int nf = 0; nf < 4; ++nf) {
                h[mi][r][nf] -= mu;
                s2 += h[mi][r][nf] * h[mi][r][nf];
            }
            s2 += __shfl_xor(s2, 1); s2 += __shfl_xor(s2, 2);
            s2 += __shfl_xor(s2, 4); s2 += __shfl_xor(s2, 8);
            if (cb == 0) red[1][rl][wc] = s2;
        }
    __syncthreads();
    #pragma unroll
    for (int mi = 0; mi < 2; ++mi)
        #pragma unroll
        for (int r = 0; r < 4; ++r) {
            const int rl = wr * 32 + mi * 16 + rg * 4 + r;
            const int t = t0 + rl;
            const float var = (red[1][rl][0] + red[1][rl][1]) * (1.f / 128.f);
            const float rstd = 1.f / sqrtf(var + kEps);
            if (t < kNwin) {
                unsigned short* dst = encb + ((size_t)(b * kS + t)) * kH;
                #pragma unroll
                for (int nf = 0; nf < 4; ++nf) {
                    float v = gelu_exact(h[mi][r][nf] * rstd * gv[nf] + btv[nf]);
                    dst[wc * 64 + nf * 16 + cb] = f2h(v);
                }
            }
        }
}

// ================= comparator (512 thr): L1 16r x 64c, L2 16r x 32c =================
constexpr int EPP = 72;

__global__ __launch_bounds__(512, 4)
void cmp_kernel(const unsigned short* __restrict__ encb,
                const unsigned short* __restrict__ W1F, const float* __restrict__ b1,
                const unsigned short* __restrict__ W2F, const float* __restrict__ b2,
                const float* __restrict__ W3, const float* __restrict__ b3,
                float* __restrict__ out, int* __restrict__ fcnt, unsigned* __restrict__ flist)
{
    __shared__ __align__(16) unsigned short pool[12800];
    __shared__ float prm[192];

    unsigned short* esh  = pool;
    unsigned short* wt1h = pool + 4608;

    const int tid = threadIdx.x, b = blockIdx.y, t0 = blockIdx.x * 64;
    const int l = tid & 63, w = tid >> 6;
    const int wr = w >> 1, wc = w & 1;
    const int cb = l & 15, rg = l >> 4;

    if (tid < 128) prm[tid] = b1[tid];
    else if (tid < 192) prm[tid] = b2[tid - 128];

    f32x4 acc1[4];
    #pragma unroll
    for (int nf = 0; nf < 4; ++nf) acc1[nf] = f32x4{0.f, 0.f, 0.f, 0.f};

    for (int kc = 0; kc < 4; ++kc) {
        const int ro = (kc < 2) ? 0 : kW, co = (kc & 1) * 64;
        __syncthreads();
        GLD16(W1F + (size_t)kc * 8192 + w * 512 + l * 8, &wt1h[w * 512]);
        GLD16(W1F + (size_t)kc * 8192 + 4096 + w * 512 + l * 8, &wt1h[4096 + w * 512]);
        {
            const int r = tid >> 3, qq = tid & 7;
            int gr = t0 + ro + r; if (gr > kNwin - 1) gr = kNwin - 1;
            *reinterpret_cast<ush8*>(&esh[r * EPP + qq * 8]) =
                *reinterpret_cast<const ush8*>(encb + ((size_t)(b * kS + gr)) * kH + co + qq * 8);
        }
        __syncthreads();
        #pragma unroll
        for (int ks = 0; ks < 2; ++ks) {
            const int ao = (wr * 16 + cb) * EPP + ks * 32 + rg * 8;
            half8 ah = *reinterpret_cast<const half8*>(&esh[ao]);
            #pragma unroll
            for (int nf = 0; nf < 4; ++nf) {
                const int bo = (ks * 4 + rg) * 1024 + (wc * 64 + nf * 16 + cb) * 8;
                half8 bh = *reinterpret_cast<const half8*>(&wt1h[bo]);
                acc1[nf] = __builtin_amdgcn_mfma_f32_16x16x32_f16(ah, bh, acc1[nf], 0, 0, 0);
            }
        }
    }
    __syncthreads();
    unsigned short* z1h = pool;
    unsigned short* w2h = pool + 8704;
    #pragma unroll
    for (int r = 0; r < 4; ++r) {
        const int row = wr * 16 + rg * 4 + r;
        #pragma unroll
        for (int nf = 0; nf < 4; ++nf) {
            const int col = wc * 64 + nf * 16 + cb;
            z1h[row * 136 + col] = f2h(gelu_exact(acc1[nf][r] + prm[col]));
        }
    }

    f32x4 acc2[2];
    #pragma unroll
    for (int nf = 0; nf < 2; ++nf) acc2[nf] = f32x4{0.f, 0.f, 0.f, 0.f};

    for (int kc2 = 0; kc2 < 2; ++kc2) {
        __syncthreads();
        GLD16(W2F + (size_t)kc2 * 4096 + w * 512 + l * 8, &w2h[w * 512]);
        __syncthreads();
        #pragma unroll
        for (int ks = 0; ks < 2; ++ks) {
            const int ao = (wr * 16 + cb) * 136 + kc2 * 64 + ks * 32 + rg * 8;
            half8 ah = *reinterpret_cast<const half8*>(&z1h[ao]);
            #pragma unroll
            for (int nf = 0; nf < 2; ++nf) {
                const int bo = (ks * 4 + rg) * 512 + (wc * 32 + nf * 16 + cb) * 8;
                half8 bh = *reinterpret_cast<const half8*>(&w2h[bo]);
                acc2[nf] = __builtin_amdgcn_mfma_f32_16x16x32_f16(ah, bh, acc2[nf], 0, 0, 0);
            }
        }
    }
    __syncthreads();
    float* z2f = reinterpret_cast<float*>(pool);
    #pragma unroll
    for (int r = 0; r < 4; ++r) {
        const int row = wr * 16 + rg * 4 + r;
        #pragma unroll
        for (int nf = 0; nf < 2; ++nf) {
            const int col = wc * 32 + nf * 16 + cb;
            z2f[row * 68 + col] = gelu_exact(acc2[nf][r] + prm[128 + col]);
        }
    }
    __syncthreads();

    if (tid < 64) {
        const int t = t0 + tid;
        if (t < kT) {
            float s = 0.f;
            #pragma unroll 8
            for (int k = 0; k < 64; ++k) s = fmaf(z2f[tid * 68 + k], W3[k], s);
            const float p = 1.f / (1.f + expf(-(s + b3[0])));
            out[(size_t)b * kS + t + kW] = p;
            out[(size_t)kB * kS + (size_t)b * kS + t + kW] = (p > 0.5f) ? 1.f : 0.f;
            if (fabsf(p - 0.5f) < kMargin) {
                int idx = atomicAdd(fcnt, 1);
                if (idx < FCAP) flist[idx] = ((unsigned)b << 16) | (unsigned)t;
            }
        }
    }
}

// ================= fix3: fp32 recompute, 8 positions per block (W amortized 8x) =================
__global__ __launch_bounds__(256, 2)
void fix3_kernel(const float* __restrict__ x, const float* __restrict__ Wenc,
                 const float* __restrict__ benc, const float* __restrict__ gma,
                 const float* __restrict__ bta, const float* __restrict__ W1,
                 const float* __restrict__ b1, const float* __restrict__ W2,
                 const float* __restrict__ b2, const float* __restrict__ W3,
                 const float* __restrict__ b3, const int* __restrict__ fcnt,
                 const unsigned* __restrict__ flist, float* __restrict__ out)
{
    __shared__ float xw[1280 * 8];    // [j = r*640+k][p], 40 KB; reads are wave-broadcast
    __shared__ float es[8][256];      // 8 KB
    __shared__ float z1s[8][128];     // 4 KB
    __shared__ float z2s[8][64];      // 2 KB
    __shared__ float wredA[4][8];
    __shared__ float wredB[4][8];
    __shared__ unsigned pbt[8];

    const int tid = threadIdx.x;
    int n = *fcnt; if (n > FCAP) n = FCAP;
    const int nb = (n + 7) >> 3;

    for (int ib = blockIdx.x; ib < nb; ib += gridDim.x) {
        __syncthreads();                           // guard reuse across ib iterations
        if (tid < 8) {
            int idx = ib * 8 + tid; if (idx > n - 1) idx = n - 1;
            pbt[tid] = flist[idx];
        }
        __syncthreads();
        // stage 8 windows (each contiguous 1280 floats starting at row t)
        #pragma unroll
        for (int p = 0; p < 8; ++p) {
            const unsigned e = pbt[p];
            const int bb = (int)(e >> 16), tt = (int)(e & 0xFFFF);
            const float4* src = reinterpret_cast<const float4*>(
                x + ((size_t)bb * kS + tt) * kI);
            for (int j4 = tid; j4 < 320; j4 += 256) {
                float4 v = src[j4];
                float* dst = &xw[(j4 * 4) * 8 + p];
                dst[0] = v.x; dst[8] = v.y; dst[16] = v.z; dst[24] = v.w;
            }
        }
        __syncthreads();

        const int r = tid >> 7, c = tid & 127;     // wave = r*2 + (c>>6)
        const int wv = tid >> 6;
        float acc[8];
        #pragma unroll
        for (int p = 0; p < 8; ++p) acc[p] = 0.f;
        {
            const float* wp = Wenc + c;
            const int jb = r * 640;
            #pragma unroll 8
            for (int k = 0; k < 640; ++k) {
                const float wvv = wp[(size_t)k * kH];
                const float4 lo = *reinterpret_cast<const float4*>(&xw[(jb + k) * 8]);
                const float4 hi = *reinterpret_cast<const float4*>(&xw[(jb + k) * 8 + 4]);
                acc[0] = fmaf(lo.x, wvv, acc[0]);
                acc[1] = fmaf(lo.y, wvv, acc[1]);
                acc[2] = fmaf(lo.z, wvv, acc[2]);
                acc[3] = fmaf(lo.w, wvv, acc[3]);
                acc[4] = fmaf(hi.x, wvv, acc[4]);
                acc[5] = fmaf(hi.y, wvv, acc[5]);
                acc[6] = fmaf(hi.z, wvv, acc[6]);
                acc[7] = fmaf(hi.w, wvv, acc[7]);
            }
        }
        const float bc = benc[c];
        float hv[8];
        #pragma unroll
        for (int p = 0; p < 8; ++p) {
            hv[p] = acc[p] + bc;
            float s = hv[p];
            #pragma unroll
            for (int m = 1; m < 64; m <<= 1) s += __shfl_xor(s, m, 64);
            if ((tid & 63) == 0) wredA[wv][p] = s;
        }
        __syncthreads();
        #pragma unroll
        for (int p = 0; p < 8; ++p) {
            const float mu = (wredA[r * 2][p] + wredA[r * 2 + 1][p]) * (1.f / 128.f);
            hv[p] -= mu;
            float s2 = hv[p] * hv[p];
            #pragma unroll
            for (int m = 1; m < 64; m <<= 1) s2 += __shfl_xor(s2, m, 64);
            if ((tid & 63) == 0) wredB[wv][p] = s2;
        }
        __syncthreads();
        {
            const float gc = gma[c], btc = bta[c];
            #pragma unroll
            for (int p = 0; p < 8; ++p) {
                const float var = (wredB[r * 2][p] + wredB[r * 2 + 1][p]) * (1.f / 128.f);
                es[p][r * 128 + c] = gelu_exact(hv[p] * (1.f / sqrtf(var + kEps)) * gc + btc);
            }
        }
        __syncthreads();
        {   // layer 1: thread (ph = tid>>7, j = tid&127) handles p = ph*4..+3
            const int ph = tid >> 7, j = tid & 127;
            float z[4] = {0.f, 0.f, 0.f, 0.f};
            #pragma unroll 4
            for (int k = 0; k < 256; ++k) {
                const float w1v = W1[(size_t)k * kH + j];
                #pragma unroll
                for (int pp = 0; pp < 4; ++pp)
                    z[pp] = fmaf(es[ph * 4 + pp][k], w1v, z[pp]);
            }
            const float b1j = b1[j];
            #pragma unroll
            for (int pp = 0; pp < 4; ++pp)
                z1s[ph * 4 + pp][j] = gelu_exact(z[pp] + b1j);
        }
        __syncthreads();
        {   // layer 2: thread (ph2 = tid>>6, j = tid&63) handles p = ph2*2..+1
            const int ph2 = tid >> 6, j = tid & 63;
            float z[2] = {0.f, 0.f};
            #pragma unroll 4
            for (int k = 0; k < 128; ++k) {
                const float w2v = W2[(size_t)k * 64 + j];
                #pragma unroll
                for (int pp = 0; pp < 2; ++pp)
                    z[pp] = fmaf(z1s[ph2 * 2 + pp][k], w2v, z[pp]);
            }
            const float b2j = b2[j];
            #pragma unroll
            for (int pp = 0; pp < 2; ++pp)
                z2s[ph2 * 2 + pp][j] = gelu_exact(z[pp] + b2j);
        }
        __syncthreads();
        {   // layer 3: p = tid>>5, q = tid&31
            const int p = tid >> 5, q = tid & 31;
            float s = z2s[p][q] * W3[q] + z2s[p][q + 32] * W3[q + 32];
            s += __shfl_xor(s, 1); s += __shfl_xor(s, 2); s += __shfl_xor(s, 4);
            s += __shfl_xor(s, 8); s += __shfl_xor(s, 16);
            if (q == 0) {
                const unsigned e = pbt[p];
                const int bb = (int)(e >> 16), tt = (int)(e & 0xFFFF);
                const float pr = 1.f / (1.f + expf(-(s + b3[0])));
                out[(size_t)bb * kS + tt + kW] = pr;
                out[(size_t)kB * kS + (size_t)bb * kS + tt + kW] = (pr > 0.5f) ? 1.f : 0.f;
            }
        }
    }
}

}  // namespace

extern "C" void kernel_launch(void* const* d_in, const int* in_sizes, int n_in,
                              void* d_out, int out_size, void* d_ws, size_t ws_size,
                              hipStream_t stream)
{
    const float* x    = (const float*)d_in[0];
    const float* Wenc = (const float*)d_in[1];
    const float* benc = (const float*)d_in[2];
    const float* gma  = (const float*)d_in[3];
    const float* bta  = (const float*)d_in[4];
    const float* W1   = (const float*)d_in[5];
    const float* b1   = (const float*)d_in[6];
    const float* W2   = (const float*)d_in[7];
    const float* b2   = (const float*)d_in[8];
    const float* W3   = (const float*)d_in[9];
    const float* b3   = (const float*)d_in[10];
    float* out = (float*)d_out;

    char* ws = (char*)d_ws;
    unsigned short* encb  = (unsigned short*)(ws + ENCB_OFF);
    unsigned short* WeF   = (unsigned short*)(ws + WEF_OFF);
    unsigned short* W1F   = (unsigned short*)(ws + W1F_OFF);
    unsigned short* W2F   = (unsigned short*)(ws + W2F_OFF);
    int* fcnt             = (int*)(ws + FC_OFF);
    unsigned* flist       = (unsigned*)(ws + FL_OFF);

    hipMemsetAsync(d_out, 0, (size_t)out_size * sizeof(float), stream);
    hipMemsetAsync(fcnt, 0, 64, stream);

    prep_kernel<<<256, 256, 0, stream>>>(Wenc, W1, W2, WeF, W1F, W2F);
    enc_kernel<<<dim3(16, kB), 512, 0, stream>>>(x, WeF, benc, gma, bta, encb);
    cmp_kernel<<<dim3(32, kB), 512, 0, stream>>>(encb, W1F, b1, W2F, b2, W3, b3,
                                                 out, fcnt, flist);
    fix3_kernel<<<1024, 256, 0, stream>>>(x, Wenc, benc, gma, bta, W1, b1, W2, b2, W3, b3,
                                          fcnt, flist, out);
}

// Round 20
// 112.619 us; speedup vs baseline: 3.1159x; 1.2063x over previous
//
#include <hip/hip_runtime.h>
#include <hip/hip_bf16.h>
#include <math.h>

namespace {

constexpr int kB = 32;
constexpr int kS = 2048;
constexpr int kI = 32;
constexpr int kW = 20;
constexpr int kH = 128;
constexpr int kNwin = kS - kW + 1;   // 2029
constexpr int kT = kS - 2 * kW;      // 2008
constexpr float kEps = 1e-5f;
constexpr int FCAP = 16384;
constexpr float kMargin = 3e-3f;     // fp16 1-pass p-error bound ~5e-4 << 3e-3

typedef __attribute__((ext_vector_type(8))) _Float16 half8;       // 8 f16 (4 VGPR)
typedef __attribute__((ext_vector_type(8))) unsigned short ush8;  // 16B unit
typedef __attribute__((ext_vector_type(4))) float f32x4;

// async global->LDS DMA, 16B per lane; dest = uniform base + lane*16 (linear)
#define GLD16(SRC, DST)                                                          \
    __builtin_amdgcn_global_load_lds(                                            \
        (const __attribute__((address_space(1))) unsigned*)(const void*)(SRC),   \
        (__attribute__((address_space(3))) unsigned*)(void*)(DST), 16, 0, 0)

__device__ __forceinline__ unsigned short f2h(float f) {          // RNE f32->f16
    _Float16 h = (_Float16)f;
    return __builtin_bit_cast(unsigned short, h);
}
__device__ __forceinline__ float gelu_exact(float v) {
    return 0.5f * v * (1.0f + erff(v * 0.70710678118654752440f));
}

// ---- workspace layout (bytes) ----
constexpr size_t ENCB_OFF = 0;                        // enc f16: 32*2048*128*2 = 16 MB
constexpr size_t WEF_OFF  = 16777216;                 // WencF frag-major [20][4][128][8]
constexpr size_t W1F_OFF  = WEF_OFF + 163840;         // W1F [4][2][4][128][8]
constexpr size_t W2F_OFF  = W1F_OFF + 65536;          // W2F [2][2][4][64][8]
constexpr size_t FC_OFF   = W2F_OFF + 16384;
constexpr size_t FL_OFF   = FC_OFF + 64;              // flist FCAP u32 (64 KB)

// ================= prep: frag-major f16 W layouts =================
__global__ void prep_kernel(const float* __restrict__ Wenc, const float* __restrict__ W1,
                            const float* __restrict__ W2,
                            unsigned short* __restrict__ WeF, unsigned short* __restrict__ W1F,
                            unsigned short* __restrict__ W2F)
{
    const int tid = blockIdx.x * blockDim.x + threadIdx.x;
    const int nth = gridDim.x * blockDim.x;
    for (int i = tid; i < 20 * 4 * 128 * 8; i += nth) {
        int j = i & 7, n = (i >> 3) & 127, rg = (i >> 10) & 3, kc = i >> 12;
        int k = kc * 32 + rg * 8 + j;
        WeF[i] = f2h(Wenc[(size_t)k * kH + n]);
    }
    for (int i = tid; i < 4 * 2 * 4 * 128 * 8; i += nth) {
        int j = i & 7, n = (i >> 3) & 127, rg = (i >> 10) & 3, ks = (i >> 12) & 1, kc = i >> 13;
        int k = kc * 64 + ks * 32 + rg * 8 + j;
        W1F[i] = f2h(W1[(size_t)k * kH + n]);
    }
    for (int i = tid; i < 2 * 2 * 4 * 64 * 8; i += nth) {
        int j = i & 7, n = (i >> 3) & 63, rg = (i >> 9) & 3, ks = (i >> 11) & 1, kc2 = i >> 12;
        int k = kc2 * 64 + ks * 32 + rg * 8 + j;
        W2F[i] = f2h(W2[(size_t)k * 64 + n]);
    }
}

// ================= encoder: f16 MFMA + LN + GELU (512 thr, 2D wave tile) =================
constexpr int AP = 40;    // x LDS pitch in ushorts (80B)

__global__ __launch_bounds__(512, 4)
void enc_kernel(const float* __restrict__ x, const unsigned short* __restrict__ WeF,
                const float* __restrict__ benc, const float* __restrict__ gma,
                const float* __restrict__ bta, unsigned short* __restrict__ encb)
{
    __shared__ unsigned short xsh[147 * AP];
    __shared__ unsigned short wth[4096];
    __shared__ float red[2][128][2];

    const int tid = threadIdx.x, b = blockIdx.y, t0 = blockIdx.x * 128;
    const int l = tid & 63, w = tid >> 6;
    const int wr = w >> 1, wc = w & 1;
    const int cb = l & 15, rg = l >> 4;

    const float4* x4 = reinterpret_cast<const float4*>(x + (size_t)b * kS * kI);
    for (int i = tid; i < 147 * 8; i += 512) {
        int r = i >> 3, q = i & 7;
        int gr = t0 + r; if (gr > kS - 1) gr = kS - 1;
        float4 v = x4[gr * 8 + q];
        unsigned short h0 = f2h(v.x), h1 = f2h(v.y), h2 = f2h(v.z), h3 = f2h(v.w);
        *reinterpret_cast<uint2*>(&xsh[r * AP + q * 4]) =
            make_uint2((unsigned)h0 | ((unsigned)h1 << 16), (unsigned)h2 | ((unsigned)h3 << 16));
    }

    f32x4 acc[2][4];
    #pragma unroll
    for (int mi = 0; mi < 2; ++mi)
        #pragma unroll
        for (int nf = 0; nf < 4; ++nf) acc[mi][nf] = f32x4{0.f, 0.f, 0.f, 0.f};

    for (int kc = 0; kc < 20; ++kc) {
        __syncthreads();
        GLD16(WeF + (size_t)kc * 4096 + w * 512 + l * 8, &wth[w * 512]);
        __syncthreads();
        const int a0o = (wr * 32 + cb + kc) * AP + rg * 8;
        half8 a0 = *reinterpret_cast<const half8*>(&xsh[a0o]);
        half8 a1 = *reinterpret_cast<const half8*>(&xsh[a0o + 16 * AP]);
        #pragma unroll
        for (int nf = 0; nf < 4; ++nf) {
            const int bo = rg * 1024 + (wc * 64 + nf * 16 + cb) * 8;
            half8 bh = *reinterpret_cast<const half8*>(&wth[bo]);
            acc[0][nf] = __builtin_amdgcn_mfma_f32_16x16x32_f16(a0, bh, acc[0][nf], 0, 0, 0);
            acc[1][nf] = __builtin_amdgcn_mfma_f32_16x16x32_f16(a1, bh, acc[1][nf], 0, 0, 0);
        }
    }

    float bv[4], gv[4], btv[4];
    #pragma unroll
    for (int nf = 0; nf < 4; ++nf) {
        const int col = wc * 64 + nf * 16 + cb;
        bv[nf] = benc[col]; gv[nf] = gma[col]; btv[nf] = bta[col];
    }
    float h[2][4][4];
    #pragma unroll
    for (int mi = 0; mi < 2; ++mi)
        #pragma unroll
        for (int r = 0; r < 4; ++r) {
            float s = 0.f;
            #pragma unroll
            for (int nf = 0; nf < 4; ++nf) {
                h[mi][r][nf] = acc[mi][nf][r] + bv[nf];
                s += h[mi][r][nf];
            }
            s += __shfl_xor(s, 1); s += __shfl_xor(s, 2);
            s += __shfl_xor(s, 4); s += __shfl_xor(s, 8);
            if (cb == 0) red[0][wr * 32 + mi * 16 + rg * 4 + r][wc] = s;
        }
    __syncthreads();
    #pragma unroll
    for (int mi = 0; mi < 2; ++mi)
        #pragma unroll
        for (int r = 0; r < 4; ++r) {
            const int rl = wr * 32 + mi * 16 + rg * 4 + r;
            const float mu = (red[0][rl][0] + red[0][rl][1]) * (1.f / 128.f);
            float s2 = 0.f;
            #pragma unroll
            for (int nf = 0; nf < 4; ++nf) {
                h[mi][r][nf] -= mu;
                s2 += h[mi][r][nf] * h[mi][r][nf];
            }
            s2 += __shfl_xor(s2, 1); s2 += __shfl_xor(s2, 2);
            s2 += __shfl_xor(s2, 4); s2 += __shfl_xor(s2, 8);
            if (cb == 0) red[1][rl][wc] = s2;
        }
    __syncthreads();
    #pragma unroll
    for (int mi = 0; mi < 2; ++mi)
        #pragma unroll
        for (int r = 0; r < 4; ++r) {
            const int rl = wr * 32 + mi * 16 + rg * 4 + r;
            const int t = t0 + rl;
            const float var = (red[1][rl][0] + red[1][rl][1]) * (1.f / 128.f);
            const float rstd = 1.f / sqrtf(var + kEps);
            if (t < kNwin) {
                unsigned short* dst = encb + ((size_t)(b * kS + t)) * kH;
                #pragma unroll
                for (int nf = 0; nf < 4; ++nf) {
                    float v = gelu_exact(h[mi][r][nf] * rstd * gv[nf] + btv[nf]);
                    dst[wc * 64 + nf * 16 + cb] = f2h(v);
                }
            }
        }
}

// ================= comparator (512 thr): L1 16r x 64c, L2 16r x 32c =================
constexpr int EPP = 72;

__global__ __launch_bounds__(512, 4)
void cmp_kernel(const unsigned short* __restrict__ encb,
                const unsigned short* __restrict__ W1F, const float* __restrict__ b1,
                const unsigned short* __restrict__ W2F, const float* __restrict__ b2,
                const float* __restrict__ W3, const float* __restrict__ b3,
                float* __restrict__ out, int* __restrict__ fcnt, unsigned* __restrict__ flist)
{
    __shared__ __align__(16) unsigned short pool[12800];
    __shared__ float prm[192];

    unsigned short* esh  = pool;
    unsigned short* wt1h = pool + 4608;

    const int tid = threadIdx.x, b = blockIdx.y, t0 = blockIdx.x * 64;
    const int l = tid & 63, w = tid >> 6;
    const int wr = w >> 1, wc = w & 1;
    const int cb = l & 15, rg = l >> 4;

    if (tid < 128) prm[tid] = b1[tid];
    else if (tid < 192) prm[tid] = b2[tid - 128];

    f32x4 acc1[4];
    #pragma unroll
    for (int nf = 0; nf < 4; ++nf) acc1[nf] = f32x4{0.f, 0.f, 0.f, 0.f};

    for (int kc = 0; kc < 4; ++kc) {
        const int ro = (kc < 2) ? 0 : kW, co = (kc & 1) * 64;
        __syncthreads();
        GLD16(W1F + (size_t)kc * 8192 + w * 512 + l * 8, &wt1h[w * 512]);
        GLD16(W1F + (size_t)kc * 8192 + 4096 + w * 512 + l * 8, &wt1h[4096 + w * 512]);
        {
            const int r = tid >> 3, qq = tid & 7;
            int gr = t0 + ro + r; if (gr > kNwin - 1) gr = kNwin - 1;
            *reinterpret_cast<ush8*>(&esh[r * EPP + qq * 8]) =
                *reinterpret_cast<const ush8*>(encb + ((size_t)(b * kS + gr)) * kH + co + qq * 8);
        }
        __syncthreads();
        #pragma unroll
        for (int ks = 0; ks < 2; ++ks) {
            const int ao = (wr * 16 + cb) * EPP + ks * 32 + rg * 8;
            half8 ah = *reinterpret_cast<const half8*>(&esh[ao]);
            #pragma unroll
            for (int nf = 0; nf < 4; ++nf) {
                const int bo = (ks * 4 + rg) * 1024 + (wc * 64 + nf * 16 + cb) * 8;
                half8 bh = *reinterpret_cast<const half8*>(&wt1h[bo]);
                acc1[nf] = __builtin_amdgcn_mfma_f32_16x16x32_f16(ah, bh, acc1[nf], 0, 0, 0);
            }
        }
    }
    __syncthreads();
    unsigned short* z1h = pool;
    unsigned short* w2h = pool + 8704;
    #pragma unroll
    for (int r = 0; r < 4; ++r) {
        const int row = wr * 16 + rg * 4 + r;
        #pragma unroll
        for (int nf = 0; nf < 4; ++nf) {
            const int col = wc * 64 + nf * 16 + cb;
            z1h[row * 136 + col] = f2h(gelu_exact(acc1[nf][r] + prm[col]));
        }
    }

    f32x4 acc2[2];
    #pragma unroll
    for (int nf = 0; nf < 2; ++nf) acc2[nf] = f32x4{0.f, 0.f, 0.f, 0.f};

    for (int kc2 = 0; kc2 < 2; ++kc2) {
        __syncthreads();
        GLD16(W2F + (size_t)kc2 * 4096 + w * 512 + l * 8, &w2h[w * 512]);
        __syncthreads();
        #pragma unroll
        for (int ks = 0; ks < 2; ++ks) {
            const int ao = (wr * 16 + cb) * 136 + kc2 * 64 + ks * 32 + rg * 8;
            half8 ah = *reinterpret_cast<const half8*>(&z1h[ao]);
            #pragma unroll
            for (int nf = 0; nf < 2; ++nf) {
                const int bo = (ks * 4 + rg) * 512 + (wc * 32 + nf * 16 + cb) * 8;
                half8 bh = *reinterpret_cast<const half8*>(&w2h[bo]);
                acc2[nf] = __builtin_amdgcn_mfma_f32_16x16x32_f16(ah, bh, acc2[nf], 0, 0, 0);
            }
        }
    }
    __syncthreads();
    float* z2f = reinterpret_cast<float*>(pool);
    #pragma unroll
    for (int r = 0; r < 4; ++r) {
        const int row = wr * 16 + rg * 4 + r;
        #pragma unroll
        for (int nf = 0; nf < 2; ++nf) {
            const int col = wc * 32 + nf * 16 + cb;
            z2f[row * 68 + col] = gelu_exact(acc2[nf][r] + prm[128 + col]);
        }
    }
    __syncthreads();

    if (tid < 64) {
        const int t = t0 + tid;
        if (t < kT) {
            float s = 0.f;
            #pragma unroll 8
            for (int k = 0; k < 64; ++k) s = fmaf(z2f[tid * 68 + k], W3[k], s);
            const float p = 1.f / (1.f + expf(-(s + b3[0])));
            out[(size_t)b * kS + t + kW] = p;
            out[(size_t)kB * kS + (size_t)b * kS + t + kW] = (p > 0.5f) ? 1.f : 0.f;
            if (fabsf(p - 0.5f) < kMargin) {
                int idx = atomicAdd(fcnt, 1);
                if (idx < FCAP) flist[idx] = ((unsigned)b << 16) | (unsigned)t;
            }
        }
    }
}

// ================= fix4: fp32 recompute, 8 pos/block, W chunk-staged in LDS via DMA =================
// threads: p = tid>>5 (position), cq = tid&31 (4 cols each). All W inner reads from LDS.
__global__ __launch_bounds__(256, 2)
void fix4_kernel(const float* __restrict__ x, const float* __restrict__ Wenc,
                 const float* __restrict__ benc, const float* __restrict__ gma,
                 const float* __restrict__ bta, const float* __restrict__ W1,
                 const float* __restrict__ b1, const float* __restrict__ W2,
                 const float* __restrict__ b2, const float* __restrict__ W3,
                 const float* __restrict__ b3, const int* __restrict__ fcnt,
                 const unsigned* __restrict__ flist, float* __restrict__ out)
{
    __shared__ float Wc[8192];        // 32 KB: current W chunk [kk][cols]
    __shared__ float xwc[1024];       // [r][p][kk]: (r*8+p)*64+kk
    __shared__ float es[2048];        // [p][256]
    __shared__ float z1s[1024];       // [p][128]
    __shared__ float z2s[512];        // [p][64]
    __shared__ unsigned pbt[8];

    const int tid = threadIdx.x;
    const int wv = tid >> 6, l = tid & 63;
    const int p = tid >> 5, cq = tid & 31;
    int n = *fcnt; if (n > FCAP) n = FCAP;
    if (n <= 0) return;
    const int nb = (n + 7) >> 3;

    for (int ib = blockIdx.x; ib < nb; ib += gridDim.x) {
        __syncthreads();
        if (tid < 8) {
            int idx = ib * 8 + tid; if (idx > n - 1) idx = n - 1;
            pbt[tid] = flist[idx];
        }
        __syncthreads();

        // ---- encoder GEMM: h[r][c] = sum_k win[k] * Wenc[k][c], K=640 in 10 chunks
        float acc[2][4];
        #pragma unroll
        for (int r = 0; r < 2; ++r)
            #pragma unroll
            for (int j = 0; j < 4; ++j) acc[r][j] = 0.f;

        for (int kc = 0; kc < 10; ++kc) {
            __syncthreads();                       // prior chunk reads done
            {   // DMA Wenc chunk (contiguous 32 KB)
                const float* src = Wenc + (size_t)kc * 8192;
                #pragma unroll
                for (int q = 0; q < 8; ++q)
                    GLD16(src + (wv * 8 + q) * 256 + l * 4, &Wc[(wv * 8 + q) * 256]);
            }
            {   // stage xwc: 256 float4 units (kq 16, pp 8, r 2)
                const int kq = tid & 15, pp = (tid >> 4) & 7, r = tid >> 7;
                const unsigned e = pbt[pp];
                const int bb = (int)(e >> 16), tt = (int)(e & 0xFFFF);
                const float4 v = *reinterpret_cast<const float4*>(
                    x + ((size_t)bb * kS + tt + r * kW) * kI + kc * 64 + kq * 4);
                *reinterpret_cast<float4*>(&xwc[(r * 8 + pp) * 64 + kq * 4]) = v;
            }
            __syncthreads();                       // DMA + ds_writes complete
            #pragma unroll 4
            for (int kk = 0; kk < 64; ++kk) {
                const float a0 = xwc[p * 64 + kk];
                const float a1 = xwc[(8 + p) * 64 + kk];
                const float4 wv4 = *reinterpret_cast<const float4*>(&Wc[kk * 128 + cq * 4]);
                acc[0][0] = fmaf(a0, wv4.x, acc[0][0]);
                acc[0][1] = fmaf(a0, wv4.y, acc[0][1]);
                acc[0][2] = fmaf(a0, wv4.z, acc[0][2]);
                acc[0][3] = fmaf(a0, wv4.w, acc[0][3]);
                acc[1][0] = fmaf(a1, wv4.x, acc[1][0]);
                acc[1][1] = fmaf(a1, wv4.y, acc[1][1]);
                acc[1][2] = fmaf(a1, wv4.z, acc[1][2]);
                acc[1][3] = fmaf(a1, wv4.w, acc[1][3]);
            }
        }

        // ---- LN + GELU (per (p,r) row; row lives in one 32-lane group)
        const float4 bv = *reinterpret_cast<const float4*>(benc + cq * 4);
        const float4 gv = *reinterpret_cast<const float4*>(gma + cq * 4);
        const float4 bt = *reinterpret_cast<const float4*>(bta + cq * 4);
        #pragma unroll
        for (int r = 0; r < 2; ++r) {
            float hv[4];
            hv[0] = acc[r][0] + bv.x; hv[1] = acc[r][1] + bv.y;
            hv[2] = acc[r][2] + bv.z; hv[3] = acc[r][3] + bv.w;
            float s = hv[0] + hv[1] + hv[2] + hv[3];
            s += __shfl_xor(s, 1); s += __shfl_xor(s, 2); s += __shfl_xor(s, 4);
            s += __shfl_xor(s, 8); s += __shfl_xor(s, 16);
            const float mu = s * (1.f / 128.f);
            float s2 = 0.f;
            #pragma unroll
            for (int j = 0; j < 4; ++j) { hv[j] -= mu; s2 += hv[j] * hv[j]; }
            s2 += __shfl_xor(s2, 1); s2 += __shfl_xor(s2, 2); s2 += __shfl_xor(s2, 4);
            s2 += __shfl_xor(s2, 8); s2 += __shfl_xor(s2, 16);
            const float rstd = 1.f / sqrtf(s2 * (1.f / 128.f) + kEps);
            float o[4];
            o[0] = gelu_exact(hv[0] * rstd * gv.x + bt.x);
            o[1] = gelu_exact(hv[1] * rstd * gv.y + bt.y);
            o[2] = gelu_exact(hv[2] * rstd * gv.z + bt.z);
            o[3] = gelu_exact(hv[3] * rstd * gv.w + bt.w);
            *reinterpret_cast<float4*>(&es[p * 256 + r * 128 + cq * 4]) =
                make_float4(o[0], o[1], o[2], o[3]);
        }

        // ---- layer 1: z1[j] = gelu(sum_k es[k] * W1[k][j] + b1), K=256, N=128
        {
            float z[4] = {0.f, 0.f, 0.f, 0.f};
            for (int kc1 = 0; kc1 < 4; ++kc1) {
                __syncthreads();                   // prior Wc reads done
                const float* src = W1 + (size_t)kc1 * 8192;
                #pragma unroll
                for (int q = 0; q < 8; ++q)
                    GLD16(src + (wv * 8 + q) * 256 + l * 4, &Wc[(wv * 8 + q) * 256]);
                __syncthreads();
                #pragma unroll 4
                for (int kk = 0; kk < 64; ++kk) {
                    const float a = es[p * 256 + kc1 * 64 + kk];
                    const float4 wv4 = *reinterpret_cast<const float4*>(&Wc[kk * 128 + cq * 4]);
                    z[0] = fmaf(a, wv4.x, z[0]);
                    z[1] = fmaf(a, wv4.y, z[1]);
                    z[2] = fmaf(a, wv4.z, z[2]);
                    z[3] = fmaf(a, wv4.w, z[3]);
                }
            }
            const float4 b1v = *reinterpret_cast<const float4*>(b1 + cq * 4);
            *reinterpret_cast<float4*>(&z1s[p * 128 + cq * 4]) = make_float4(
                gelu_exact(z[0] + b1v.x), gelu_exact(z[1] + b1v.y),
                gelu_exact(z[2] + b1v.z), gelu_exact(z[3] + b1v.w));
        }

        // ---- layer 2: K=128, N=64 (W2 = 32 KB, staged whole; jq<16 active)
        __syncthreads();                           // layer-1 Wc reads done
        {
            #pragma unroll
            for (int q = 0; q < 8; ++q)
                GLD16(W2 + (wv * 8 + q) * 256 + l * 4, &Wc[(wv * 8 + q) * 256]);
        }
        __syncthreads();
        if (cq < 16) {
            float z[4] = {0.f, 0.f, 0.f, 0.f};
            #pragma unroll 4
            for (int kk = 0; kk < 128; ++kk) {
                const float a = z1s[p * 128 + kk];
                const float4 wv4 = *reinterpret_cast<const float4*>(&Wc[kk * 64 + cq * 4]);
                z[0] = fmaf(a, wv4.x, z[0]);
                z[1] = fmaf(a, wv4.y, z[1]);
                z[2] = fmaf(a, wv4.z, z[2]);
                z[3] = fmaf(a, wv4.w, z[3]);
            }
            const float4 b2v = *reinterpret_cast<const float4*>(b2 + cq * 4);
            *reinterpret_cast<float4*>(&z2s[p * 64 + cq * 4]) = make_float4(
                gelu_exact(z[0] + b2v.x), gelu_exact(z[1] + b2v.y),
                gelu_exact(z[2] + b2v.z), gelu_exact(z[3] + b2v.w));
        }
        __syncthreads();

        // ---- layer 3: dot(z2, W3) + sigmoid
        {
            float s = z2s[p * 64 + cq] * W3[cq] + z2s[p * 64 + cq + 32] * W3[cq + 32];
            s += __shfl_xor(s, 1); s += __shfl_xor(s, 2); s += __shfl_xor(s, 4);
            s += __shfl_xor(s, 8); s += __shfl_xor(s, 16);
            if (cq == 0) {
                const unsigned e = pbt[p];
                const int bb = (int)(e >> 16), tt = (int)(e & 0xFFFF);
                const float pr = 1.f / (1.f + expf(-(s + b3[0])));
                out[(size_t)bb * kS + tt + kW] = pr;
                out[(size_t)kB * kS + (size_t)bb * kS + tt + kW] = (pr > 0.5f) ? 1.f : 0.f;
            }
        }
    }
}

}  // namespace

extern "C" void kernel_launch(void* const* d_in, const int* in_sizes, int n_in,
                              void* d_out, int out_size, void* d_ws, size_t ws_size,
                              hipStream_t stream)
{
    const float* x    = (const float*)d_in[0];
    const float* Wenc = (const float*)d_in[1];
    const float* benc = (const float*)d_in[2];
    const float* gma  = (const float*)d_in[3];
    const float* bta  = (const float*)d_in[4];
    const float* W1   = (const float*)d_in[5];
    const float* b1   = (const float*)d_in[6];
    const float* W2   = (const float*)d_in[7];
    const float* b2   = (const float*)d_in[8];
    const float* W3   = (const float*)d_in[9];
    const float* b3   = (const float*)d_in[10];
    float* out = (float*)d_out;

    char* ws = (char*)d_ws;
    unsigned short* encb  = (unsigned short*)(ws + ENCB_OFF);
    unsigned short* WeF   = (unsigned short*)(ws + WEF_OFF);
    unsigned short* W1F   = (unsigned short*)(ws + W1F_OFF);
    unsigned short* W2F   = (unsigned short*)(ws + W2F_OFF);
    int* fcnt             = (int*)(ws + FC_OFF);
    unsigned* flist       = (unsigned*)(ws + FL_OFF);

    hipMemsetAsync(d_out, 0, (size_t)out_size * sizeof(float), stream);
    hipMemsetAsync(fcnt, 0, 64, stream);

    prep_kernel<<<256, 256, 0, stream>>>(Wenc, W1, W2, WeF, W1F, W2F);
    enc_kernel<<<dim3(16, kB), 512, 0, stream>>>(x, WeF, benc, gma, bta, encb);
    cmp_kernel<<<dim3(32, kB), 512, 0, stream>>>(encb, W1F, b1, W2F, b2, W3, b3,
                                                 out, fcnt, flist);
    fix4_kernel<<<512, 256, 0, stream>>>(x, Wenc, benc, gma, bta, W1, b1, W2, b2, W3, b3,
                                         fcnt, flist, out);
}